// Round 3
// baseline (478.965 us; speedup 1.0000x reference)
//
#include <hip/hip_runtime.h>

// Bottom-up HTMM upward pass. LDS-free upsweep: lane (g,j) owns the
// child-state-j component of every node; octet (8 lanes sharing g)
// butterflies perform the j-reduction. Tree structure is implicit:
// starts[d]=(8^d-1)/7, child position == local_index % 8 at every level.

constexpr int NT_NODES = 299593;
constexpr int S0 = 0, S1 = 1, S2 = 9, S3 = 73, S4 = 585, S5 = 4681, S6 = 37449;

// ---------------- stage 0: parameter softmaxes -> tables in ws ----------------
// Layouts (float):
//   Mt  [g][j][l][i] : 16*8*8*8 = 8192   (= smSP[l,g]*smA[i,j,l,g])
//   smBt[m][g][c]    : 32*16*8  = 4096
//   smPit[g][c][l]   : 16*8*8   = 1024   (= smPi[c,l,g])
//   wt  [l][m][g]    : 8*32*16  = 4096   (= sum_c smPi[c,l,g]*smB[c,m,g])
__global__ __launch_bounds__(256) void stage0(
    const float* __restrict__ A, const float* __restrict__ B,
    const float* __restrict__ Pi, const float* __restrict__ SP,
    float* __restrict__ Mt, float* __restrict__ smBt,
    float* __restrict__ smPit, float* __restrict__ wt)
{
    __shared__ float spg[128];                    // [l][g]
    __shared__ __align__(16) float bL[4096];      // [m][g][c]
    __shared__ __align__(16) float piL[1024];     // [l][g][c]
    int tid = threadIdx.x;

    if (tid < 16) {
        int g = tid;
        float v[8]; float mx = -1e30f;
        #pragma unroll
        for (int l = 0; l < 8; ++l) { v[l] = SP[l * 16 + g]; mx = fmaxf(mx, v[l]); }
        float s = 0.f;
        #pragma unroll
        for (int l = 0; l < 8; ++l) { v[l] = __expf(v[l] - mx); s += v[l]; }
        float r = 1.f / s;
        #pragma unroll
        for (int l = 0; l < 8; ++l) spg[l * 16 + g] = v[l] * r;
    }
    __syncthreads();

    // A: tasks (g,j,l), softmax over i (stride C*K*G = 1024)
    for (int v = tid; v < 1024; v += 256) {
        int g = v & 15, rem = v >> 4, j = rem & 7, l = rem >> 3;
        float a[8]; float mx = -1e30f;
        #pragma unroll
        for (int i = 0; i < 8; ++i) { a[i] = A[((i * 8 + j) * 8 + l) * 16 + g]; mx = fmaxf(mx, a[i]); }
        float s = 0.f;
        #pragma unroll
        for (int i = 0; i < 8; ++i) { a[i] = __expf(a[i] - mx); s += a[i]; }
        float scale = spg[l * 16 + g] / s;
        #pragma unroll
        for (int i = 0; i < 8; ++i) Mt[((g * 8 + j) * 8 + l) * 8 + i] = a[i] * scale;
    }

    if (tid < 128) {
        // smB: (c,g), softmax over m (axis 1, stride G)
        int c = tid >> 4, g = tid & 15;
        float vv[32]; float mx = -1e30f;
        #pragma unroll
        for (int m = 0; m < 32; ++m) { vv[m] = B[(c * 32 + m) * 16 + g]; mx = fmaxf(mx, vv[m]); }
        float s = 0.f;
        #pragma unroll
        for (int m = 0; m < 32; ++m) { vv[m] = __expf(vv[m] - mx); s += vv[m]; }
        float r = 1.f / s;
        #pragma unroll
        for (int m = 0; m < 32; ++m) {
            float p = vv[m] * r;
            smBt[(m * 16 + g) * 8 + c] = p;
            bL[(m * 16 + g) * 8 + c] = p;
        }
    } else {
        // smPi: (l,g), softmax over c (axis 0, stride K*G = 128)
        int v = tid - 128; int l = v >> 4, g = v & 15;
        float a[8]; float mx = -1e30f;
        #pragma unroll
        for (int c = 0; c < 8; ++c) { a[c] = Pi[(c * 8 + l) * 16 + g]; mx = fmaxf(mx, a[c]); }
        float s = 0.f;
        #pragma unroll
        for (int c = 0; c < 8; ++c) { a[c] = __expf(a[c] - mx); s += a[c]; }
        float r = 1.f / s;
        #pragma unroll
        for (int c = 0; c < 8; ++c) {
            float p = a[c] * r;
            smPit[(g * 8 + c) * 8 + l] = p;
            piL[(l * 16 + g) * 8 + c] = p;
        }
    }
    __syncthreads();

    // wt: tasks (l,m,g) — dot over c of piL and bL
    for (int v = tid; v < 4096; v += 256) {
        int g = v & 15, rem = v >> 4, m = rem & 31, l = rem >> 5;
        const float4* pb = (const float4*)(bL + (m * 16 + g) * 8);
        const float4* pp = (const float4*)(piL + (l * 16 + g) * 8);
        float4 b0 = pb[0], b1 = pb[1], p0 = pp[0], p1 = pp[1];
        float s = (b0.x * p0.x + b0.y * p0.y) + (b0.z * p0.z + b0.w * p0.w)
                + (b1.x * p1.x + b1.y * p1.y) + (b1.z * p1.z + b1.w * p1.w);
        wt[(l * 32 + m) * 16 + g] = s;
    }
}

// static 1-of-8 select by lane bits (7 cndmask, all indices compile-time)
__device__ __forceinline__ float sel8(const float v[8], bool c0, bool c1, bool c2) {
    float a0 = c0 ? v[1] : v[0];
    float a1 = c0 ? v[3] : v[2];
    float a2 = c0 ? v[5] : v[4];
    float a3 = c0 ? v[7] : v[6];
    float b0 = c1 ? a1 : a0;
    float b1 = c1 ? a3 : a2;
    return c2 ? b1 : b0;
}

// ---------------- upsweep: one block = one depth-2 subtree, zero LDS ----------------
// tid = g*8 + j  (g = generator, j = child hidden state).
template <bool LEAF>
__global__ __launch_bounds__(128, 4) void upsweep(
    const float* __restrict__ Mt, const float* __restrict__ smBt,
    const float* __restrict__ smPit, const float* __restrict__ wt,
    const int* __restrict__ x,
    const float* __restrict__ srcBeta, float* __restrict__ dstBeta,
    float* __restrict__ llout, const float* __restrict__ llin,
    int bpt, int s_mid, int s_root)
{
    int b = blockIdx.x;
    int t = b / bpt;
    int loc = b - t * bpt;
    int tid = threadIdx.x;
    int g = tid >> 3, j = tid & 7;
    bool c0 = (j & 1) != 0, c1 = (j & 2) != 0, c2 = (j & 4) != 0;
    const int nodebase = t * NT_NODES;

    // fold previous stage's per-block ll partials (per-lane distinct)
    float ll_priv = 0.f;
    if (llin) {
        const float* p = llin + ((size_t)b * 64 + (size_t)j * 8) * 16 + g;
        float a0 = p[0], a1 = p[16], a2 = p[32], a3 = p[48];
        float a4 = p[64], a5 = p[80], a6 = p[96], a7 = p[112];
        ll_priv = ((a0 + a1) + (a2 + a3)) + ((a4 + a5) + (a6 + a7));
    }

    // M[l][i] = smSP[l]*smA[i, myj, l, myg]
    float M[64];
    {
        const float4* mp = (const float4*)(Mt + tid * 64);
        #pragma unroll
        for (int v = 0; v < 16; ++v) {
            float4 f = mp[v];
            M[4 * v + 0] = f.x; M[4 * v + 1] = f.y;
            M[4 * v + 2] = f.z; M[4 * v + 3] = f.w;
        }
    }

    float pi[8];
    int xq = 0;
    if constexpr (LEAF) {
        const float4* pp = (const float4*)(smPit + tid * 8);
        float4 p0 = pp[0], p1 = pp[1];
        pi[0] = p0.x; pi[1] = p0.y; pi[2] = p0.z; pi[3] = p0.w;
        pi[4] = p1.x; pi[5] = p1.y; pi[6] = p1.z; pi[7] = p1.w;
        xq = x[nodebase + S6 + loc * 64 + (tid & 63)];
    }
    int xm = x[nodebase + s_mid + loc * 8 + (tid & 7)];

    float ll = 0.f;     // octet-identical tree contributions
    float bmid[8];      // my-j component of each mid parent's beta

    #pragma unroll
    for (int u = 0; u < 8; ++u) {
        float bch[8];
        if constexpr (LEAF) {
            float nupp = 1.f;
            #pragma unroll
            for (int l = 0; l < 8; ++l) {
                int xv = __shfl(xq, u * 8 + l);            // uniform broadcast
                float bj = smBt[xv * 128 + tid];           // [xv][g][j]
                float nu = wt[(l * 32 + xv) * 16 + g];     // octet-broadcast
                bch[l] = pi[l] * bj * __builtin_amdgcn_rcpf(nu);
                nupp *= nu;
                if (l & 1) { ll += __logf(nupp); nupp = 1.f; }
            }
        } else {
            const float* sb = srcBeta + ((size_t)b * 64 + u * 8) * 128 + tid;
            #pragma unroll
            for (int l = 0; l < 8; ++l) bch[l] = sb[l * 128];
        }

        // pa[i] = sum_l bch[l] * M[l][i]   (in-lane, own j)
        float pa[8];
        #pragma unroll
        for (int i = 0; i < 8; ++i) {
            float s = bch[0] * M[0 * 8 + i];
            #pragma unroll
            for (int l = 1; l < 8; ++l) s = fmaf(bch[l], M[l * 8 + i], s);
            pa[i] = s;
        }
        // octet butterfly all-reduce over j
        #pragma unroll
        for (int m = 1; m <= 4; m <<= 1) {
            #pragma unroll
            for (int i = 0; i < 8; ++i) pa[i] += __shfl_xor(pa[i], m);
        }
        // emission + normalize
        int xv = __shfl(xm, u);
        const float4* bp = (const float4*)(smBt + xv * 128 + g * 8);
        float4 b0 = bp[0], b1 = bp[1];
        pa[0] *= b0.x; pa[1] *= b0.y; pa[2] *= b0.z; pa[3] *= b0.w;
        pa[4] *= b1.x; pa[5] *= b1.y; pa[6] *= b1.z; pa[7] *= b1.w;
        float nu = ((pa[0] + pa[1]) + (pa[2] + pa[3])) + ((pa[4] + pa[5]) + (pa[6] + pa[7]));
        ll += __logf(nu);
        bmid[u] = sel8(pa, c0, c1, c2) * __builtin_amdgcn_rcpf(nu);
    }

    // root of this block's subtree (children = mid parents, position u)
    {
        float pa[8];
        #pragma unroll
        for (int i = 0; i < 8; ++i) {
            float s = bmid[0] * M[0 * 8 + i];
            #pragma unroll
            for (int l = 1; l < 8; ++l) s = fmaf(bmid[l], M[l * 8 + i], s);
            pa[i] = s;
        }
        #pragma unroll
        for (int m = 1; m <= 4; m <<= 1) {
            #pragma unroll
            for (int i = 0; i < 8; ++i) pa[i] += __shfl_xor(pa[i], m);
        }
        int xv = x[nodebase + s_root + loc];
        const float4* bp = (const float4*)(smBt + xv * 128 + g * 8);
        float4 b0 = bp[0], b1 = bp[1];
        pa[0] *= b0.x; pa[1] *= b0.y; pa[2] *= b0.z; pa[3] *= b0.w;
        pa[4] *= b1.x; pa[5] *= b1.y; pa[6] *= b1.z; pa[7] *= b1.w;
        float nu = ((pa[0] + pa[1]) + (pa[2] + pa[3])) + ((pa[4] + pa[5]) + (pa[6] + pa[7]));
        ll += __logf(nu);
        dstBeta[(size_t)b * 128 + tid] = sel8(pa, c0, c1, c2) * __builtin_amdgcn_rcpf(nu);
    }

    // llout[b*16+g]: octet-reduce the private part, add octet-identical part
    float s = ll_priv;
    s += __shfl_xor(s, 1); s += __shfl_xor(s, 2); s += __shfl_xor(s, 4);
    if (j == 0) llout[b * 16 + g] = s + ll;
}

extern "C" void kernel_launch(void* const* d_in, const int* in_sizes, int n_in,
                              void* d_out, int out_size, void* d_ws, size_t ws_size,
                              hipStream_t stream)
{
    const float* A  = (const float*)d_in[0];
    const float* B  = (const float*)d_in[1];
    const float* Pi = (const float*)d_in[2];
    const float* SP = (const float*)d_in[3];
    const int*   x  = (const int*)d_in[4];

    float* ws    = (float*)d_ws;
    float* Mt    = ws;                    // 8192
    float* smBt  = Mt + 8192;             // 4096
    float* smPit = smBt + 4096;           // 1024
    float* wt    = smPit + 1024;          // 4096
    float* lv4   = wt + 4096;             // 8192*128 = 1048576
    float* lv2   = lv4 + 1048576;         // 128*128 = 16384
    float* lv0   = lv2 + 16384;           // 2*128 = 256
    float* ll1   = lv0 + 256;             // 8192*16 = 131072
    float* ll2   = ll1 + 131072;          // 128*16 = 2048
    float* out   = (float*)d_out;

    stage0<<<1, 256, 0, stream>>>(A, B, Pi, SP, Mt, smBt, smPit, wt);
    // levels 6 -> 5 -> 4
    upsweep<true><<<8192, 128, 0, stream>>>(Mt, smBt, smPit, wt, x, nullptr, lv4, ll1,
                                            nullptr, 4096, S5, S4);
    // levels 4 -> 3 -> 2  (+ fold ll1)
    upsweep<false><<<128, 128, 0, stream>>>(Mt, smBt, smPit, wt, x, lv4, lv2, ll2,
                                            ll1, 64, S3, S2);
    // levels 2 -> 1 -> 0  (+ fold ll2), writes out[2][16] directly
    upsweep<false><<<2, 128, 0, stream>>>(Mt, smBt, smPit, wt, x, lv2, lv0, out,
                                          ll2, 1, S1, S0);
}

// Round 4
// 161.306 us; speedup vs baseline: 2.9693x; 2.9693x over previous
//
#include <hip/hip_runtime.h>

// Bottom-up HTMM upward pass. LDS-free upsweep: lane (g,j) owns the
// child-state-j component of every node; octet (8 lanes sharing g)
// butterflies perform the j-reduction. Tree structure is implicit:
// starts[d]=(8^d-1)/7, child position == local_index % 8 at every level.

constexpr int NT_NODES = 299593;
constexpr int S0 = 0, S1 = 1, S2 = 9, S3 = 73, S4 = 585, S5 = 4681, S6 = 37449;

// ---------------- stage 0: parameter softmaxes -> tables in ws ----------------
// Layouts (float):
//   Mt  [g][j][l][i] : 16*8*8*8 = 8192   (= smSP[l,g]*smA[i,j,l,g])
//   smBt[m][g][c]    : 32*16*8  = 4096
//   smPit[g][c][l]   : 16*8*8   = 1024   (= smPi[c,l,g])
//   wt  [l][m][g]    : 8*32*16  = 4096   (= sum_c smPi[c,l,g]*smB[c,m,g])
__global__ __launch_bounds__(256) void stage0(
    const float* __restrict__ A, const float* __restrict__ B,
    const float* __restrict__ Pi, const float* __restrict__ SP,
    float* __restrict__ Mt, float* __restrict__ smBt,
    float* __restrict__ smPit, float* __restrict__ wt)
{
    __shared__ float spg[128];                    // [l][g]
    __shared__ __align__(16) float bL[4096];      // [m][g][c]
    __shared__ __align__(16) float piL[1024];     // [l][g][c]
    int tid = threadIdx.x;

    if (tid < 16) {
        int g = tid;
        float v[8]; float mx = -1e30f;
        #pragma unroll
        for (int l = 0; l < 8; ++l) { v[l] = SP[l * 16 + g]; mx = fmaxf(mx, v[l]); }
        float s = 0.f;
        #pragma unroll
        for (int l = 0; l < 8; ++l) { v[l] = __expf(v[l] - mx); s += v[l]; }
        float r = 1.f / s;
        #pragma unroll
        for (int l = 0; l < 8; ++l) spg[l * 16 + g] = v[l] * r;
    }
    __syncthreads();

    // A: tasks (g,j,l), softmax over i (stride C*K*G = 1024)
    for (int v = tid; v < 1024; v += 256) {
        int g = v & 15, rem = v >> 4, j = rem & 7, l = rem >> 3;
        float a[8]; float mx = -1e30f;
        #pragma unroll
        for (int i = 0; i < 8; ++i) { a[i] = A[((i * 8 + j) * 8 + l) * 16 + g]; mx = fmaxf(mx, a[i]); }
        float s = 0.f;
        #pragma unroll
        for (int i = 0; i < 8; ++i) { a[i] = __expf(a[i] - mx); s += a[i]; }
        float scale = spg[l * 16 + g] / s;
        #pragma unroll
        for (int i = 0; i < 8; ++i) Mt[((g * 8 + j) * 8 + l) * 8 + i] = a[i] * scale;
    }

    if (tid < 128) {
        // smB: (c,g), softmax over m (axis 1, stride G)
        int c = tid >> 4, g = tid & 15;
        float vv[32]; float mx = -1e30f;
        #pragma unroll
        for (int m = 0; m < 32; ++m) { vv[m] = B[(c * 32 + m) * 16 + g]; mx = fmaxf(mx, vv[m]); }
        float s = 0.f;
        #pragma unroll
        for (int m = 0; m < 32; ++m) { vv[m] = __expf(vv[m] - mx); s += vv[m]; }
        float r = 1.f / s;
        #pragma unroll
        for (int m = 0; m < 32; ++m) {
            float p = vv[m] * r;
            smBt[(m * 16 + g) * 8 + c] = p;
            bL[(m * 16 + g) * 8 + c] = p;
        }
    } else {
        // smPi: (l,g), softmax over c (axis 0, stride K*G = 128)
        int v = tid - 128; int l = v >> 4, g = v & 15;
        float a[8]; float mx = -1e30f;
        #pragma unroll
        for (int c = 0; c < 8; ++c) { a[c] = Pi[(c * 8 + l) * 16 + g]; mx = fmaxf(mx, a[c]); }
        float s = 0.f;
        #pragma unroll
        for (int c = 0; c < 8; ++c) { a[c] = __expf(a[c] - mx); s += a[c]; }
        float r = 1.f / s;
        #pragma unroll
        for (int c = 0; c < 8; ++c) {
            float p = a[c] * r;
            smPit[(g * 8 + c) * 8 + l] = p;
            piL[(l * 16 + g) * 8 + c] = p;
        }
    }
    __syncthreads();

    // wt: tasks (l,m,g) — dot over c of piL and bL
    for (int v = tid; v < 4096; v += 256) {
        int g = v & 15, rem = v >> 4, m = rem & 31, l = rem >> 5;
        const float4* pb = (const float4*)(bL + (m * 16 + g) * 8);
        const float4* pp = (const float4*)(piL + (l * 16 + g) * 8);
        float4 b0 = pb[0], b1 = pb[1], p0 = pp[0], p1 = pp[1];
        float s = (b0.x * p0.x + b0.y * p0.y) + (b0.z * p0.z + b0.w * p0.w)
                + (b1.x * p1.x + b1.y * p1.y) + (b1.z * p1.z + b1.w * p1.w);
        wt[(l * 32 + m) * 16 + g] = s;
    }
}

// static 1-of-8 select by lane bits (7 cndmask, all indices compile-time)
__device__ __forceinline__ float sel8(const float v[8], bool c0, bool c1, bool c2) {
    float a0 = c0 ? v[1] : v[0];
    float a1 = c0 ? v[3] : v[2];
    float a2 = c0 ? v[5] : v[4];
    float a3 = c0 ? v[7] : v[6];
    float b0 = c1 ? a1 : a0;
    float b1 = c1 ? a3 : a2;
    return c2 ? b1 : b0;
}

// ---------------- upsweep: one block = one depth-2 subtree, zero LDS ----------------
// tid = g*8 + j  (g = generator, j = child hidden state).
// __launch_bounds__(128, 2): VGPR cap 256 — the kernel needs ~120 live VGPRs
// (M[64] + bch/pa/bmid/pi). (128,4) clamped to 64 VGPR and spilled M[] to
// scratch -> 1.5 GB HBM traffic/dispatch (round-3 regression).
template <bool LEAF>
__global__ __launch_bounds__(128, 2) void upsweep(
    const float* __restrict__ Mt, const float* __restrict__ smBt,
    const float* __restrict__ smPit, const float* __restrict__ wt,
    const int* __restrict__ x,
    const float* __restrict__ srcBeta, float* __restrict__ dstBeta,
    float* __restrict__ llout, const float* __restrict__ llin,
    int bpt, int s_mid, int s_root)
{
    int b = blockIdx.x;
    int t = b / bpt;
    int loc = b - t * bpt;
    int tid = threadIdx.x;
    int g = tid >> 3, j = tid & 7;
    bool c0 = (j & 1) != 0, c1 = (j & 2) != 0, c2 = (j & 4) != 0;
    const int nodebase = t * NT_NODES;

    // fold previous stage's per-block ll partials (per-lane distinct)
    float ll_priv = 0.f;
    if (llin) {
        const float* p = llin + ((size_t)b * 64 + (size_t)j * 8) * 16 + g;
        float a0 = p[0], a1 = p[16], a2 = p[32], a3 = p[48];
        float a4 = p[64], a5 = p[80], a6 = p[96], a7 = p[112];
        ll_priv = ((a0 + a1) + (a2 + a3)) + ((a4 + a5) + (a6 + a7));
    }

    // M[l][i] = smSP[l]*smA[i, myj, l, myg]
    float M[64];
    {
        const float4* mp = (const float4*)(Mt + tid * 64);
        #pragma unroll
        for (int v = 0; v < 16; ++v) {
            float4 f = mp[v];
            M[4 * v + 0] = f.x; M[4 * v + 1] = f.y;
            M[4 * v + 2] = f.z; M[4 * v + 3] = f.w;
        }
    }

    float pi[8];
    int xq = 0;
    if constexpr (LEAF) {
        const float4* pp = (const float4*)(smPit + tid * 8);
        float4 p0 = pp[0], p1 = pp[1];
        pi[0] = p0.x; pi[1] = p0.y; pi[2] = p0.z; pi[3] = p0.w;
        pi[4] = p1.x; pi[5] = p1.y; pi[6] = p1.z; pi[7] = p1.w;
        xq = x[nodebase + S6 + loc * 64 + (tid & 63)];
    }
    int xm = x[nodebase + s_mid + loc * 8 + (tid & 7)];

    float ll = 0.f;     // octet-identical tree contributions
    float bmid[8];      // my-j component of each mid parent's beta

    #pragma unroll
    for (int u = 0; u < 8; ++u) {
        float bch[8];
        if constexpr (LEAF) {
            float nupp = 1.f;
            #pragma unroll
            for (int l = 0; l < 8; ++l) {
                int xv = __shfl(xq, u * 8 + l);            // uniform broadcast
                float bj = smBt[xv * 128 + tid];           // [xv][g][j]
                float nu = wt[(l * 32 + xv) * 16 + g];     // octet-broadcast
                bch[l] = pi[l] * bj * __builtin_amdgcn_rcpf(nu);
                nupp *= nu;
                if (l & 1) { ll += __logf(nupp); nupp = 1.f; }
            }
        } else {
            const float* sb = srcBeta + ((size_t)b * 64 + u * 8) * 128 + tid;
            #pragma unroll
            for (int l = 0; l < 8; ++l) bch[l] = sb[l * 128];
        }

        // pa[i] = sum_l bch[l] * M[l][i]   (in-lane, own j)
        float pa[8];
        #pragma unroll
        for (int i = 0; i < 8; ++i) {
            float s = bch[0] * M[0 * 8 + i];
            #pragma unroll
            for (int l = 1; l < 8; ++l) s = fmaf(bch[l], M[l * 8 + i], s);
            pa[i] = s;
        }
        // octet butterfly all-reduce over j
        #pragma unroll
        for (int m = 1; m <= 4; m <<= 1) {
            #pragma unroll
            for (int i = 0; i < 8; ++i) pa[i] += __shfl_xor(pa[i], m);
        }
        // emission + normalize
        int xv = __shfl(xm, u);
        const float4* bp = (const float4*)(smBt + xv * 128 + g * 8);
        float4 b0 = bp[0], b1 = bp[1];
        pa[0] *= b0.x; pa[1] *= b0.y; pa[2] *= b0.z; pa[3] *= b0.w;
        pa[4] *= b1.x; pa[5] *= b1.y; pa[6] *= b1.z; pa[7] *= b1.w;
        float nu = ((pa[0] + pa[1]) + (pa[2] + pa[3])) + ((pa[4] + pa[5]) + (pa[6] + pa[7]));
        ll += __logf(nu);
        bmid[u] = sel8(pa, c0, c1, c2) * __builtin_amdgcn_rcpf(nu);
    }

    // root of this block's subtree (children = mid parents, position u)
    {
        float pa[8];
        #pragma unroll
        for (int i = 0; i < 8; ++i) {
            float s = bmid[0] * M[0 * 8 + i];
            #pragma unroll
            for (int l = 1; l < 8; ++l) s = fmaf(bmid[l], M[l * 8 + i], s);
            pa[i] = s;
        }
        #pragma unroll
        for (int m = 1; m <= 4; m <<= 1) {
            #pragma unroll
            for (int i = 0; i < 8; ++i) pa[i] += __shfl_xor(pa[i], m);
        }
        int xv = x[nodebase + s_root + loc];
        const float4* bp = (const float4*)(smBt + xv * 128 + g * 8);
        float4 b0 = bp[0], b1 = bp[1];
        pa[0] *= b0.x; pa[1] *= b0.y; pa[2] *= b0.z; pa[3] *= b0.w;
        pa[4] *= b1.x; pa[5] *= b1.y; pa[6] *= b1.z; pa[7] *= b1.w;
        float nu = ((pa[0] + pa[1]) + (pa[2] + pa[3])) + ((pa[4] + pa[5]) + (pa[6] + pa[7]));
        ll += __logf(nu);
        dstBeta[(size_t)b * 128 + tid] = sel8(pa, c0, c1, c2) * __builtin_amdgcn_rcpf(nu);
    }

    // llout[b*16+g]: octet-reduce the private part, add octet-identical part
    float s = ll_priv;
    s += __shfl_xor(s, 1); s += __shfl_xor(s, 2); s += __shfl_xor(s, 4);
    if (j == 0) llout[b * 16 + g] = s + ll;
}

extern "C" void kernel_launch(void* const* d_in, const int* in_sizes, int n_in,
                              void* d_out, int out_size, void* d_ws, size_t ws_size,
                              hipStream_t stream)
{
    const float* A  = (const float*)d_in[0];
    const float* B  = (const float*)d_in[1];
    const float* Pi = (const float*)d_in[2];
    const float* SP = (const float*)d_in[3];
    const int*   x  = (const int*)d_in[4];

    float* ws    = (float*)d_ws;
    float* Mt    = ws;                    // 8192
    float* smBt  = Mt + 8192;             // 4096
    float* smPit = smBt + 4096;           // 1024
    float* wt    = smPit + 1024;          // 4096
    float* lv4   = wt + 4096;             // 8192*128 = 1048576
    float* lv2   = lv4 + 1048576;         // 128*128 = 16384
    float* lv0   = lv2 + 16384;           // 2*128 = 256
    float* ll1   = lv0 + 256;             // 8192*16 = 131072
    float* ll2   = ll1 + 131072;          // 128*16 = 2048
    float* out   = (float*)d_out;

    stage0<<<1, 256, 0, stream>>>(A, B, Pi, SP, Mt, smBt, smPit, wt);
    // levels 6 -> 5 -> 4
    upsweep<true><<<8192, 128, 0, stream>>>(Mt, smBt, smPit, wt, x, nullptr, lv4, ll1,
                                            nullptr, 4096, S5, S4);
    // levels 4 -> 3 -> 2  (+ fold ll1)
    upsweep<false><<<128, 128, 0, stream>>>(Mt, smBt, smPit, wt, x, lv4, lv2, ll2,
                                            ll1, 64, S3, S2);
    // levels 2 -> 1 -> 0  (+ fold ll2), writes out[2][16] directly
    upsweep<false><<<2, 128, 0, stream>>>(Mt, smBt, smPit, wt, x, lv2, lv0, out,
                                          ll2, 1, S1, S0);
}

// Round 5
// 88.121 us; speedup vs baseline: 5.4353x; 1.8305x over previous
//
#include <hip/hip_runtime.h>

// Bottom-up HTMM upward pass.
// Hot kernels: thread = (mid-parent, generator g); each wave = 64 consecutive
// mid-parents of ONE g (wave-uniform), so the transition matrix M[g] streams
// through SCALAR loads (SGPR broadcast) and the 512-FMA sweep runs with zero
// cross-lane ops. Children betas live in 64 registers per thread. Only the
// per-subtree root uses an 8-lane butterfly (1/9 of the work).
// Tree structure is implicit: starts[d]=(8^d-1)/7, child position == local%8.

constexpr int NT_NODES = 299593;
constexpr int S0 = 0, S1 = 1, S2 = 9, S3 = 73, S4 = 585, S5 = 4681, S6 = 37449;

// ---------------- stage 0: parameter softmaxes -> tables in ws ----------------
// New layouts (g-outermost for wave-uniform scalar access):
//   MtN   [g][l][j][i] : 8192  (= smSP[l,g]*smA[i,j,l,g])
//   smBtN [g][m][c]    : 4096
//   smPitN[g][l][c]    : 1024  (= smPi[c,l,g])
//   wtN   [g][l][m]    : 4096  (= sum_c smPi[c,l,g]*smB[c,m,g])
// Old layouts (for the tiny tail kernel, per-thread (g,j) slices):
//   Mt_old  [g][j][l][i] : 8192
//   smBt_old[m][g][c]    : 4096
__global__ __launch_bounds__(256) void stage0(
    const float* __restrict__ A, const float* __restrict__ B,
    const float* __restrict__ Pi, const float* __restrict__ SP,
    float* __restrict__ Mt_old, float* __restrict__ MtN,
    float* __restrict__ smBt_old, float* __restrict__ smBtN,
    float* __restrict__ smPitN, float* __restrict__ wtN)
{
    __shared__ float spg[128];                    // [l][g]
    __shared__ __align__(16) float bL[4096];      // [m][g][c]
    __shared__ __align__(16) float piL[1024];     // [l][g][c]
    int tid = threadIdx.x;

    if (tid < 16) {
        int g = tid;
        float v[8]; float mx = -1e30f;
        #pragma unroll
        for (int l = 0; l < 8; ++l) { v[l] = SP[l * 16 + g]; mx = fmaxf(mx, v[l]); }
        float s = 0.f;
        #pragma unroll
        for (int l = 0; l < 8; ++l) { v[l] = __expf(v[l] - mx); s += v[l]; }
        float r = 1.f / s;
        #pragma unroll
        for (int l = 0; l < 8; ++l) spg[l * 16 + g] = v[l] * r;
    }
    __syncthreads();

    // A: tasks (g,j,l), softmax over i (stride C*K*G = 1024)
    for (int v = tid; v < 1024; v += 256) {
        int g = v & 15, rem = v >> 4, j = rem & 7, l = rem >> 3;
        float a[8]; float mx = -1e30f;
        #pragma unroll
        for (int i = 0; i < 8; ++i) { a[i] = A[((i * 8 + j) * 8 + l) * 16 + g]; mx = fmaxf(mx, a[i]); }
        float s = 0.f;
        #pragma unroll
        for (int i = 0; i < 8; ++i) { a[i] = __expf(a[i] - mx); s += a[i]; }
        float scale = spg[l * 16 + g] / s;
        #pragma unroll
        for (int i = 0; i < 8; ++i) {
            float m = a[i] * scale;
            Mt_old[((g * 8 + j) * 8 + l) * 8 + i] = m;
            MtN[((g * 8 + l) * 8 + j) * 8 + i] = m;
        }
    }

    if (tid < 128) {
        // smB: (c,g), softmax over m (axis 1, stride G)
        int c = tid >> 4, g = tid & 15;
        float vv[32]; float mx = -1e30f;
        #pragma unroll
        for (int m = 0; m < 32; ++m) { vv[m] = B[(c * 32 + m) * 16 + g]; mx = fmaxf(mx, vv[m]); }
        float s = 0.f;
        #pragma unroll
        for (int m = 0; m < 32; ++m) { vv[m] = __expf(vv[m] - mx); s += vv[m]; }
        float r = 1.f / s;
        #pragma unroll
        for (int m = 0; m < 32; ++m) {
            float p = vv[m] * r;
            smBt_old[(m * 16 + g) * 8 + c] = p;
            smBtN[(g * 32 + m) * 8 + c] = p;
            bL[(m * 16 + g) * 8 + c] = p;
        }
    } else {
        // smPi: (l,g), softmax over c (axis 0, stride K*G = 128)
        int v = tid - 128; int l = v >> 4, g = v & 15;
        float a[8]; float mx = -1e30f;
        #pragma unroll
        for (int c = 0; c < 8; ++c) { a[c] = Pi[(c * 8 + l) * 16 + g]; mx = fmaxf(mx, a[c]); }
        float s = 0.f;
        #pragma unroll
        for (int c = 0; c < 8; ++c) { a[c] = __expf(a[c] - mx); s += a[c]; }
        float r = 1.f / s;
        #pragma unroll
        for (int c = 0; c < 8; ++c) {
            float p = a[c] * r;
            smPitN[(g * 8 + l) * 8 + c] = p;
            piL[(l * 16 + g) * 8 + c] = p;
        }
    }
    __syncthreads();

    // wt: tasks (l,m,g) — dot over c
    for (int v = tid; v < 4096; v += 256) {
        int g = v & 15, rem = v >> 4, m = rem & 31, l = rem >> 5;
        const float4* pb = (const float4*)(bL + (m * 16 + g) * 8);
        const float4* pp = (const float4*)(piL + (l * 16 + g) * 8);
        float4 b0 = pb[0], b1 = pb[1], p0 = pp[0], p1 = pp[1];
        float s = (b0.x * p0.x + b0.y * p0.y) + (b0.z * p0.z + b0.w * p0.w)
                + (b1.x * p1.x + b1.y * p1.y) + (b1.z * p1.z + b1.w * p1.w);
        wtN[(g * 8 + l) * 32 + m] = s;
    }
}

// ---------------- main upsweep: two levels per kernel ----------------
// Block = 256 thr = 4 waves; wave = one g, 64 mid-parents (8 subtrees).
// grid.x = NSG*4 : sg = blockIdx>>2 (subtree-group), gq = blockIdx&3.
template <bool LEAF, int NSG, int SMID, int SROOT, int SRC_PT, int NSRC_TOT, int NDST_TOT>
__global__ __launch_bounds__(256) void up2(
    const float* __restrict__ MtN, const float* __restrict__ smBtN,
    const float* __restrict__ smPitN, const float* __restrict__ wtN,
    const int* __restrict__ x,
    const float* __restrict__ srcBeta,   // [g][NSRC_TOT][8] (LEAF=false)
    float* __restrict__ dstBeta,         // [g][NDST_TOT][8]
    float* __restrict__ llout,           // [g][NSG]
    const float* __restrict__ llin, int llstride)
{
    constexpr int SPT = NSG * 4;   // subtrees per tree
    int sg = blockIdx.x >> 2;
    int gq = blockIdx.x & 3;
    int wave = threadIdx.x >> 6;
    int lane = threadIdx.x & 63;
    int g = gq * 4 + wave;                        // wave-uniform
    int gu = __builtin_amdgcn_readfirstlane(g);   // force SGPR base
    int u = lane & 7;                             // mid-parent position
    int s = sg * 8 + (lane >> 3);                 // global subtree index
    int t = (s >= SPT) ? 1 : 0;
    int localS = s - t * SPT;
    int localP = localS * 8 + u;                  // mid-parent local index
    const int base = t * NT_NODES;

    float ll = 0.f;
    float bch[64];   // children betas: [l][c], fully register-resident

    if constexpr (LEAF) {
        int xl[8];
        const int xb = base + S6 + localP * 8;
        #pragma unroll
        for (int l = 0; l < 8; ++l) xl[l] = x[xb + l];
        const float* pib = smPitN + gu * 64;      // scalar (uniform)
        const float* wtb = wtN + gu * 256;
        #pragma unroll
        for (int l = 0; l < 8; ++l) {
            int xv = xl[l];
            const float4* bp = (const float4*)(smBtN + ((gu << 5) + xv) * 8);
            float4 b0 = bp[0], b1 = bp[1];
            float nu = wtb[l * 32 + xv];
            float rn = __builtin_amdgcn_rcpf(nu);
            ll += __logf(nu);
            bch[l * 8 + 0] = pib[l * 8 + 0] * b0.x * rn;
            bch[l * 8 + 1] = pib[l * 8 + 1] * b0.y * rn;
            bch[l * 8 + 2] = pib[l * 8 + 2] * b0.z * rn;
            bch[l * 8 + 3] = pib[l * 8 + 3] * b0.w * rn;
            bch[l * 8 + 4] = pib[l * 8 + 4] * b1.x * rn;
            bch[l * 8 + 5] = pib[l * 8 + 5] * b1.y * rn;
            bch[l * 8 + 6] = pib[l * 8 + 6] * b1.z * rn;
            bch[l * 8 + 7] = pib[l * 8 + 7] * b1.w * rn;
        }
    } else {
        const float4* sp = (const float4*)(srcBeta +
            ((size_t)g * NSRC_TOT + (size_t)t * SRC_PT + (size_t)localP * 8) * 8);
        #pragma unroll
        for (int v = 0; v < 16; ++v) {
            float4 f = sp[v];
            bch[4 * v + 0] = f.x; bch[4 * v + 1] = f.y;
            bch[4 * v + 2] = f.z; bch[4 * v + 3] = f.w;
        }
    }

    // transition sweep: pa[i] = sum_{l,j} bch[l][j] * M[g][l][j][i]
    // M streams through scalar loads (gu uniform, offsets compile-time).
    float pa[8] = {0.f, 0.f, 0.f, 0.f, 0.f, 0.f, 0.f, 0.f};
    const float* Mg = MtN + (gu << 9);
    #pragma unroll
    for (int k = 0; k < 64; ++k) {
        float b = bch[k];
        #pragma unroll
        for (int i = 0; i < 8; ++i) pa[i] = fmaf(b, Mg[k * 8 + i], pa[i]);
    }

    // mid emission + normalize
    float bm[8];
    {
        int xm = x[base + SMID + localP];          // coalesced (consecutive)
        const float4* ep = (const float4*)(smBtN + ((gu << 5) + xm) * 8);
        float4 e0 = ep[0], e1 = ep[1];
        pa[0] *= e0.x; pa[1] *= e0.y; pa[2] *= e0.z; pa[3] *= e0.w;
        pa[4] *= e1.x; pa[5] *= e1.y; pa[6] *= e1.z; pa[7] *= e1.w;
        float nu = ((pa[0] + pa[1]) + (pa[2] + pa[3])) + ((pa[4] + pa[5]) + (pa[6] + pa[7]));
        ll += __logf(nu);
        float rn = __builtin_amdgcn_rcpf(nu);
        #pragma unroll
        for (int c = 0; c < 8; ++c) bm[c] = pa[c] * rn;
    }

    // root: lane's partial over its own child-position u, butterfly over octet
    {
        float pr[8] = {0.f, 0.f, 0.f, 0.f, 0.f, 0.f, 0.f, 0.f};
        const float4* mr = (const float4*)(MtN + (gu << 9) + (u << 6));
        #pragma unroll
        for (int j = 0; j < 8; ++j) {
            float4 m0 = mr[j * 2], m1 = mr[j * 2 + 1];
            float b = bm[j];
            pr[0] = fmaf(b, m0.x, pr[0]); pr[1] = fmaf(b, m0.y, pr[1]);
            pr[2] = fmaf(b, m0.z, pr[2]); pr[3] = fmaf(b, m0.w, pr[3]);
            pr[4] = fmaf(b, m1.x, pr[4]); pr[5] = fmaf(b, m1.y, pr[5]);
            pr[6] = fmaf(b, m1.z, pr[6]); pr[7] = fmaf(b, m1.w, pr[7]);
        }
        #pragma unroll
        for (int m = 1; m <= 4; m <<= 1) {
            #pragma unroll
            for (int i = 0; i < 8; ++i) pr[i] += __shfl_xor(pr[i], m);
        }
        int xr = x[base + SROOT + localS];
        const float4* ep = (const float4*)(smBtN + ((gu << 5) + xr) * 8);
        float4 e0 = ep[0], e1 = ep[1];
        pr[0] *= e0.x; pr[1] *= e0.y; pr[2] *= e0.z; pr[3] *= e0.w;
        pr[4] *= e1.x; pr[5] *= e1.y; pr[6] *= e1.z; pr[7] *= e1.w;
        float nur = ((pr[0] + pr[1]) + (pr[2] + pr[3])) + ((pr[4] + pr[5]) + (pr[6] + pr[7]));
        float rr = __builtin_amdgcn_rcpf(nur);
        if (u == 0) {
            ll += __logf(nur);
            float4* dp = (float4*)(dstBeta + ((size_t)g * NDST_TOT + s) * 8);
            dp[0] = make_float4(pr[0] * rr, pr[1] * rr, pr[2] * rr, pr[3] * rr);
            dp[1] = make_float4(pr[4] * rr, pr[5] * rr, pr[6] * rr, pr[7] * rr);
        }
    }

    // fold previous-stage ll partials (1 per thread) + wave all-reduce
    if (llin) ll += llin[g * llstride + sg * 64 + lane];
    #pragma unroll
    for (int m = 1; m < 64; m <<= 1) ll += __shfl_xor(ll, m);
    if (lane == 0) llout[g * NSG + sg] = ll;
}

// static 1-of-8 select by lane bits (7 cndmask)
__device__ __forceinline__ float sel8(const float v[8], bool c0, bool c1, bool c2) {
    float a0 = c0 ? v[1] : v[0];
    float a1 = c0 ? v[3] : v[2];
    float a2 = c0 ? v[5] : v[4];
    float a3 = c0 ? v[7] : v[6];
    float b0 = c1 ? a1 : a0;
    float b1 = c1 ? a3 : a2;
    return c2 ? b1 : b0;
}

// ---------------- tail: levels 2 -> 1 -> 0, one block per tree ----------------
// Round-4 octet-butterfly kernel (2 blocks only, perf-irrelevant), adapted to
// the new [g][node][c] beta layout and [g][16] ll2 layout.
__global__ __launch_bounds__(128) void tail(
    const float* __restrict__ Mt_old, const float* __restrict__ smBt_old,
    const int* __restrict__ x, const float* __restrict__ src /* [g][128][8] */,
    float* __restrict__ out, const float* __restrict__ ll2 /* [g][16] */)
{
    int b = blockIdx.x;                 // tree
    int tid = threadIdx.x;
    int g = tid >> 3, j = tid & 7;
    bool c0 = (j & 1) != 0, c1 = (j & 2) != 0, c2 = (j & 4) != 0;
    const int nodebase = b * NT_NODES;

    float ll_priv = ll2[g * 16 + b * 8 + j];

    float M[64];
    {
        const float4* mp = (const float4*)(Mt_old + tid * 64);
        #pragma unroll
        for (int v = 0; v < 16; ++v) {
            float4 f = mp[v];
            M[4 * v + 0] = f.x; M[4 * v + 1] = f.y;
            M[4 * v + 2] = f.z; M[4 * v + 3] = f.w;
        }
    }

    int xm = x[nodebase + S1 + j];
    float ll = 0.f;
    float bmid[8];
    const float* sb = src + g * 1024 + b * 512 + j;

    #pragma unroll
    for (int u = 0; u < 8; ++u) {
        float bch[8];
        #pragma unroll
        for (int l = 0; l < 8; ++l) bch[l] = sb[(u * 8 + l) * 8];
        float pa[8];
        #pragma unroll
        for (int i = 0; i < 8; ++i) {
            float s = bch[0] * M[0 * 8 + i];
            #pragma unroll
            for (int l = 1; l < 8; ++l) s = fmaf(bch[l], M[l * 8 + i], s);
            pa[i] = s;
        }
        #pragma unroll
        for (int m = 1; m <= 4; m <<= 1) {
            #pragma unroll
            for (int i = 0; i < 8; ++i) pa[i] += __shfl_xor(pa[i], m);
        }
        int xv = __shfl(xm, u);
        const float4* bp = (const float4*)(smBt_old + xv * 128 + g * 8);
        float4 b0 = bp[0], b1 = bp[1];
        pa[0] *= b0.x; pa[1] *= b0.y; pa[2] *= b0.z; pa[3] *= b0.w;
        pa[4] *= b1.x; pa[5] *= b1.y; pa[6] *= b1.z; pa[7] *= b1.w;
        float nu = ((pa[0] + pa[1]) + (pa[2] + pa[3])) + ((pa[4] + pa[5]) + (pa[6] + pa[7]));
        ll += __logf(nu);
        bmid[u] = sel8(pa, c0, c1, c2) * __builtin_amdgcn_rcpf(nu);
    }

    {
        float pa[8];
        #pragma unroll
        for (int i = 0; i < 8; ++i) {
            float s = bmid[0] * M[0 * 8 + i];
            #pragma unroll
            for (int l = 1; l < 8; ++l) s = fmaf(bmid[l], M[l * 8 + i], s);
            pa[i] = s;
        }
        #pragma unroll
        for (int m = 1; m <= 4; m <<= 1) {
            #pragma unroll
            for (int i = 0; i < 8; ++i) pa[i] += __shfl_xor(pa[i], m);
        }
        int xv = x[nodebase + S0];
        const float4* bp = (const float4*)(smBt_old + xv * 128 + g * 8);
        float4 b0 = bp[0], b1 = bp[1];
        pa[0] *= b0.x; pa[1] *= b0.y; pa[2] *= b0.z; pa[3] *= b0.w;
        pa[4] *= b1.x; pa[5] *= b1.y; pa[6] *= b1.z; pa[7] *= b1.w;
        float nu = ((pa[0] + pa[1]) + (pa[2] + pa[3])) + ((pa[4] + pa[5]) + (pa[6] + pa[7]));
        ll += __logf(nu);
    }

    float s = ll_priv;
    s += __shfl_xor(s, 1); s += __shfl_xor(s, 2); s += __shfl_xor(s, 4);
    if (j == 0) out[b * 16 + g] = s + ll;
}

extern "C" void kernel_launch(void* const* d_in, const int* in_sizes, int n_in,
                              void* d_out, int out_size, void* d_ws, size_t ws_size,
                              hipStream_t stream)
{
    const float* A  = (const float*)d_in[0];
    const float* B  = (const float*)d_in[1];
    const float* Pi = (const float*)d_in[2];
    const float* SP = (const float*)d_in[3];
    const int*   x  = (const int*)d_in[4];

    float* ws      = (float*)d_ws;
    float* Mt_old  = ws;                      // 8192
    float* MtN     = Mt_old + 8192;           // 8192
    float* smBt_o  = MtN + 8192;              // 4096
    float* smBtN   = smBt_o + 4096;           // 4096
    float* smPitN  = smBtN + 4096;            // 1024
    float* wtN     = smPitN + 1024;           // 4096
    float* lv4     = wtN + 4096;              // 16*8192*8 = 1048576
    float* lv2     = lv4 + 1048576;           // 16*128*8  = 16384
    float* ll1     = lv2 + 16384;             // 16*1024   = 16384
    float* ll2     = ll1 + 16384;             // 16*16     = 256
    float* out     = (float*)d_out;

    stage0<<<1, 256, 0, stream>>>(A, B, Pi, SP, Mt_old, MtN, smBt_o, smBtN, smPitN, wtN);
    // levels 6 -> 5 -> 4 : 1024 subtree-groups x 4 g-quads
    up2<true, 1024, S5, S4, 1, 1, 8192><<<4096, 256, 0, stream>>>(
        MtN, smBtN, smPitN, wtN, x, nullptr, lv4, ll1, nullptr, 0);
    // levels 4 -> 3 -> 2 : 16 subtree-groups x 4 (+ fold ll1)
    up2<false, 16, S3, S2, 4096, 8192, 128><<<64, 256, 0, stream>>>(
        MtN, smBtN, smPitN, wtN, x, lv4, lv2, ll2, ll1, 1024);
    // levels 2 -> 1 -> 0 (+ fold ll2), writes out[2][16]
    tail<<<2, 128, 0, stream>>>(Mt_old, smBt_o, x, lv2, out, ll2);
}